// Round 7
// baseline (193.090 us; speedup 1.0000x reference)
//
#include <hip/hip_runtime.h>
#include <hip/hip_bf16.h>

#define NB   32
#define SQL  2048
#define DH   128
#define QBLK 128
#define KBLK 64
#define NKT  (SQL / KBLK)      // 32 k-tiles per batch
#define TILEB 16384            // bytes per (64x128 bf16) tile image

typedef __attribute__((ext_vector_type(4)))  float f32x4;
typedef __attribute__((ext_vector_type(16))) float f32x16;
typedef __attribute__((ext_vector_type(8)))  short s16x8;
typedef __attribute__((ext_vector_type(4)))  unsigned int u32x4;

__device__ __forceinline__ unsigned int cvtpk_bf16(float lo, float hi) {
  unsigned int r;
  asm("v_cvt_pk_bf16_f32 %0, %1, %2" : "=v"(r) : "v"(lo), "v"(hi));
  return r;
}
// x.hi32 = y.lo32 ; y.lo32 = x.hi32_old  (x keeps lo, y keeps hi)
#define PLSWAP(x, y) asm volatile("v_permlane32_swap_b32 %0, %1" : "+v"(x), "+v"(y))

__device__ __forceinline__ unsigned int pk2(float lo, float hi) {
  unsigned short a = __builtin_bit_cast(unsigned short, __float2bfloat16(lo));
  unsigned short b = __builtin_bit_cast(unsigned short, __float2bfloat16(hi));
  return (unsigned int)a | ((unsigned int)b << 16);
}

#define AS1(p) ((const __attribute__((address_space(1))) void*)(p))
#define AS3(p) ((__attribute__((address_space(3))) void*)(p))

// ---------------- pass 1: K/V -> bf16 tiles in pre-swizzled LDS-image layout ----
// K image:  img[(r*256 + 2*d) ^ ((r&7)<<4)]  = bf16(K[r][d])   (r = k-row 0..63)
// Vt image: img[(d*128 + 2*k) ^ ((d&7)<<4)]  = bf16(V[k][d])   (d = 0..127, k = 0..63)
__global__ __launch_bounds__(256)
void prep_kv(const float* __restrict__ Kg, const float* __restrict__ Vg,
             char* __restrict__ wsK, char* __restrict__ wsV) {
  const int blk = blockIdx.x;          // b*32 + kt
  const int b   = blk >> 5;
  const int kt  = blk & 31;
  const int tid = threadIdx.x;
  const float* Ksrc = Kg + ((size_t)b * SQL + (size_t)kt * KBLK) * DH;
  const float* Vsrc = Vg + ((size_t)b * SQL + (size_t)kt * KBLK) * DH;
  char* Kdst = wsK + (size_t)blk * TILEB;
  char* Vdst = wsV + (size_t)blk * TILEB;

  {  // K: row-major bf16, swizzled
    const int q16 = tid & 15;          // 16B chunk (8 d-elems)
    const int r0  = tid >> 4;          // row 0..15
    #pragma unroll
    for (int it = 0; it < 4; ++it) {
      const int r = r0 + 16 * it;
      const float* src = Ksrc + (size_t)r * DH + 8 * q16;
      f32x4 a = *(const f32x4*)(src);
      f32x4 d = *(const f32x4*)(src + 4);
      u32x4 w;
      w[0] = pk2(a[0], a[1]); w[1] = pk2(a[2], a[3]);
      w[2] = pk2(d[0], d[1]); w[3] = pk2(d[2], d[3]);
      *(u32x4*)(Kdst + ((r * 256 + 16 * q16) ^ ((r & 7) << 4))) = w;
    }
  }
  {  // V: transposed Vt[d][k], swizzled (4x4 register transpose)
    const int kq = tid & 15;           // k0 = 4*kq
    const int dq = tid >> 4;           // d0 = 4*dq (+64 per it)
    #pragma unroll
    for (int it = 0; it < 2; ++it) {
      const int d0 = 4 * dq + 64 * it;
      f32x4 rv[4];
      #pragma unroll
      for (int j = 0; j < 4; ++j)
        rv[j] = *(const f32x4*)(Vsrc + (size_t)(4 * kq + j) * DH + d0);
      #pragma unroll
      for (int j2 = 0; j2 < 4; ++j2) {
        const int dd = d0 + j2;
        uint2 w = make_uint2(pk2(rv[0][j2], rv[1][j2]), pk2(rv[2][j2], rv[3][j2]));
        *(uint2*)(Vdst + ((dd * 128 + 8 * kq) ^ ((dd & 7) << 4))) = w;
      }
    }
  }
}

// ---------------- pass 2: flash attention, 32 q-rows/wave, V single-buffered ----
__global__ __launch_bounds__(256, 3)
void attn_fwd(const float* __restrict__ Qg, const char* __restrict__ wsK,
              const char* __restrict__ wsV, float* __restrict__ Og) {
  // K dbuf: 2 x 16KB @0; Vt single buf: 16KB @32768. 48KB -> 3 blocks/CU.
  __shared__ __align__(16) char smem[49152];

  const int tid  = threadIdx.x;
  const int wid  = tid >> 6;
  const int lane = tid & 63;
  const int hi   = lane >> 5;
  const int c    = lane & 31;

  // static pairing: CU pair {i, i+256} sums nt=34; all blocks of batch b share
  // i mod 8 -> same XCD under round-robin (L2 batch affinity).
  const int i    = blockIdx.x;
  const int half = i >> 8;
  const int j    = i & 255;
  const int qt   = half ? (15 - (j >> 5)) : (j >> 5);
  const int b    = j & 31;
  const int qb   = qt * QBLK;
  const int nt   = 2 * qt + 2;

  const float* Qb = Qg + (size_t)b * SQL * DH;
  float* Ob = Og + (size_t)b * SQL * DH;
  const char* Ktiles = wsK + (size_t)b * NKT * TILEB;
  const char* Vtiles = wsV + (size_t)b * NKT * TILEB;

  const float qscale = 0.08838834764831845f * 1.4426950408889634f;  // 1/sqrt(128)*log2e

  // ---- Q fragments (B-operand of swapped QK^T, 32x32x16):
  // lane (hi,c) holds Q[q = qb+32*wid+c][d = 16*ds + 8*hi + j], j=0..7
  s16x8 qf[8];
  {
    const float* qr = Qb + (size_t)(qb + 32*wid + c) * DH + 8*hi;
    #pragma unroll
    for (int ds = 0; ds < 8; ++ds) {
      f32x4 a = *(const f32x4*)(qr + 16*ds);
      f32x4 d = *(const f32x4*)(qr + 16*ds + 4);
      u32x4 w;
      w[0] = pk2(a[0]*qscale, a[1]*qscale);
      w[1] = pk2(a[2]*qscale, a[3]*qscale);
      w[2] = pk2(d[0]*qscale, d[1]*qscale);
      w[3] = pk2(d[2]*qscale, d[3]*qscale);
      qf[ds] = __builtin_bit_cast(s16x8, w);
    }
  }

  f32x16 oacc[4];
  #pragma unroll
  for (int nb = 0; nb < 4; ++nb) oacc[nb] = (f32x16){0.f};
  float m_run = -1e30f, l_run = 0.f;

  const int qglob = qb + 32*wid + c;
  const int qhiw  = qb + 32*wid + 31;
  const int qlow  = qb + 32*wid;

  // stage K tile t into Kbuf(t&1): 4 x global_load_lds, 16B/lane
  auto STAGE_K = [&](int t) {
    const char* ks = Ktiles + (size_t)t * TILEB + tid * 16;
    char* kl = smem + (t & 1) * 16384 + wid * 1024;
    #pragma unroll
    for (int jj = 0; jj < 4; ++jj)
      __builtin_amdgcn_global_load_lds(AS1(ks + jj * 4096), AS3(kl + jj * 4096), 16, 0, 0);
  };
  // stage V tile t into the single Vbuf
  auto STAGE_V = [&](int t) {
    const char* vs = Vtiles + (size_t)t * TILEB + tid * 16;
    char* vl = smem + 32768 + wid * 1024;
    #pragma unroll
    for (int jj = 0; jj < 4; ++jj)
      __builtin_amdgcn_global_load_lds(AS1(vs + jj * 4096), AS3(vl + jj * 4096), 16, 0, 0);
  };

  // prologue issue order K0, V0, K1 -> vmcnt suffixes below are exact
  STAGE_K(0);
  STAGE_V(0);
  STAGE_K(1);

  const char* Vl = smem + 32768;

  for (int t = 0; t < nt; ++t) {
    // top wait: K(t) done. Suffix left in flight: {V(t), K(t+1)} = 8 (last iter: {V(t)} = 4)
    if (t == nt - 1) asm volatile("s_waitcnt vmcnt(4)" ::: "memory");
    else             asm volatile("s_waitcnt vmcnt(8)" ::: "memory");
    __builtin_amdgcn_s_barrier();
    __builtin_amdgcn_sched_barrier(0);

    const int kb = t * KBLK;
    const char* Kl = smem + (t & 1) * 16384;
    const bool active = (kb <= qhiw);

    s16x8 pa[4];
    if (active) {
      // ---- QK^T swapped: S^T[k][q], A = K from LDS, B = Q regs
      f32x16 sacc[2];
      sacc[0] = (f32x16){0.f};
      sacc[1] = (f32x16){0.f};
      __builtin_amdgcn_s_setprio(1);
      #pragma unroll
      for (int ds = 0; ds < 8; ++ds) {
        #pragma unroll
        for (int mb = 0; mb < 2; ++mb) {
          const int row = 32*mb + c;
          s16x8 kf = *(const s16x8*)(Kl + ((row*256 + 32*ds + 16*hi) ^ ((c & 7) << 4)));
          sacc[mb] = __builtin_amdgcn_mfma_f32_32x32x16_bf16(kf, qf[ds], sacc[mb], 0, 0, 0);
        }
      }
      __builtin_amdgcn_s_setprio(0);

      // ---- causal mask (diag-crossing tiles): lane holds S^T[k=kb+32mb+crow(r,hi)][q=c]
      if (kb + KBLK - 1 > qlow) {
        #pragma unroll
        for (int mb = 0; mb < 2; ++mb)
          #pragma unroll
          for (int r = 0; r < 16; ++r) {
            const int kk = kb + 32*mb + (r & 3) + 8*(r >> 2) + 4*hi;
            if (kk > qglob) sacc[mb][r] = -1e30f;
          }
      }

      // ---- row max (tree), q = c per lane; partner half at lane^32
      float mx[8];
      #pragma unroll
      for (int e = 0; e < 8; ++e)
        mx[e] = fmaxf(fmaxf(sacc[0][e], sacc[0][e+8]), fmaxf(sacc[1][e], sacc[1][e+8]));
      mx[0] = fmaxf(mx[0], mx[4]); mx[1] = fmaxf(mx[1], mx[5]);
      mx[2] = fmaxf(mx[2], mx[6]); mx[3] = fmaxf(mx[3], mx[7]);
      float tmax = fmaxf(fmaxf(mx[0], mx[1]), fmaxf(mx[2], mx[3]));
      tmax = fmaxf(tmax, __shfl_xor(tmax, 32));

      // ---- defer-max (T13): only rescale when max grew by > 8 (log2 units)
      if (!__all(tmax <= m_run + 8.0f)) {
        const float mnew  = fmaxf(m_run, tmax);
        const float alpha = exp2f(m_run - mnew);
        #pragma unroll
        for (int r = 0; r < 16; ++r) {
          float av = __shfl(alpha, (r & 3) + 8*(r >> 2) + 4*hi);
          #pragma unroll
          for (int nb = 0; nb < 4; ++nb) oacc[nb][r] *= av;
        }
        l_run *= alpha;
        m_run = mnew;
      }

      // ---- p = exp2(s - m) interleaved with pack (low register pressure)
      float lsa = 0.f, lsb = 0.f;
      unsigned int u0[8], u1[8];
      #pragma unroll
      for (int w = 0; w < 8; ++w) {
        float p0 = exp2f(sacc[0][2*w]     - m_run);
        float p1 = exp2f(sacc[0][2*w + 1] - m_run);
        lsa += p0 + p1;
        u0[w] = cvtpk_bf16(p0, p1);
      }
      #pragma unroll
      for (int w = 0; w < 8; ++w) {
        float p0 = exp2f(sacc[1][2*w]     - m_run);
        float p1 = exp2f(sacc[1][2*w + 1] - m_run);
        lsb += p0 + p1;
        u1[w] = cvtpk_bf16(p0, p1);
      }
      float lsum = lsa + lsb;
      lsum += __shfl_xor(lsum, 32);
      l_run += lsum;

      // ---- in-register P -> PV A-frags via permlane32_swap (T12, HW-verified R4)
      PLSWAP(u0[0], u0[2]); PLSWAP(u0[1], u0[3]);
      PLSWAP(u0[4], u0[6]); PLSWAP(u0[5], u0[7]);
      PLSWAP(u1[0], u1[2]); PLSWAP(u1[1], u1[3]);
      PLSWAP(u1[4], u1[6]); PLSWAP(u1[5], u1[7]);
      { u32x4 w = {u0[0], u0[1], u0[2], u0[3]}; pa[0] = __builtin_bit_cast(s16x8, w); }
      { u32x4 w = {u0[4], u0[5], u0[6], u0[7]}; pa[1] = __builtin_bit_cast(s16x8, w); }
      { u32x4 w = {u1[0], u1[1], u1[2], u1[3]}; pa[2] = __builtin_bit_cast(s16x8, w); }
      { u32x4 w = {u1[4], u1[5], u1[6], u1[7]}; pa[3] = __builtin_bit_cast(s16x8, w); }
    }

    // mid wait: V(t) done. Suffix left: {K(t+1)} = 4 (last iter: 0).
    // Barrier OUTSIDE the active-guard (inactive waves must still arrive).
    if (t == nt - 1) asm volatile("s_waitcnt vmcnt(0)" ::: "memory");
    else             asm volatile("s_waitcnt vmcnt(4)" ::: "memory");
    __builtin_amdgcn_s_barrier();
    __builtin_amdgcn_sched_barrier(0);

    if (active) {
      // ---- PV: O[q][d] += P[q][k] Vt[d][k]^T  (A = P regs, B = V from LDS)
      __builtin_amdgcn_s_setprio(1);
      #pragma unroll
      for (int nb = 0; nb < 4; ++nb) {
        #pragma unroll
        for (int ks = 0; ks < 4; ++ks) {
          const int row = 32*nb + c;
          s16x8 vf = *(const s16x8*)(Vl + ((row*128 + 32*ks + 16*hi) ^ ((c & 7) << 4)));
          oacc[nb] = __builtin_amdgcn_mfma_f32_32x32x16_bf16(pa[ks], vf, oacc[nb], 0, 0, 0);
        }
      }
      __builtin_amdgcn_s_setprio(0);
    }

    __builtin_amdgcn_s_barrier();      // all waves done with Vbuf and Kbuf(t&1)
    if (t + 1 < nt) STAGE_V(t + 1);    // issue V before K: vmcnt suffixes exact
    if (t + 2 < nt) STAGE_K(t + 2);
  }

  // ---- epilogue: O rows q = crow(r,hi), cols d = 32nb + c
  const float linv = 1.0f / l_run;
  float* Orow = Ob + (size_t)(qb + 32*wid) * DH;
  #pragma unroll
  for (int r = 0; r < 16; ++r) {
    const int q = (r & 3) + 8*(r >> 2) + 4*hi;
    float lv = __shfl(linv, q);
    #pragma unroll
    for (int nb = 0; nb < 4; ++nb)
      Orow[(size_t)q * DH + 32*nb + c] = oacc[nb][r] * lv;
  }
}

extern "C" void kernel_launch(void* const* d_in, const int* in_sizes, int n_in,
                              void* d_out, int out_size, void* d_ws, size_t ws_size,
                              hipStream_t stream) {
  const float* Q = (const float*)d_in[0];
  const float* K = (const float*)d_in[1];
  const float* V = (const float*)d_in[2];
  // d_in[3]: causal mask, deterministic (triu k=1) -> synthesized in-kernel
  float* O = (float*)d_out;
  char* wsK = (char*)d_ws;                                   // 16 MB
  char* wsV = (char*)d_ws + (size_t)NB * NKT * TILEB;        // 16 MB

  prep_kv<<<dim3(NB * NKT), dim3(256), 0, stream>>>(K, V, wsK, wsV);
  attn_fwd<<<dim3(NB * (SQL / QBLK)), dim3(256), 0, stream>>>(Q, wsK, wsV, O);
}

// Round 9
// 93.446 us; speedup vs baseline: 2.0663x; 2.0663x over previous
//
#include <hip/hip_runtime.h>
#include <hip/hip_bf16.h>

#define NB   32
#define SQL  2048
#define DH   128
#define QBLK 128
#define KBLK 64
#define NKT  (SQL / KBLK)      // 32 k-tiles per batch
#define TILEB 16384            // bytes per (64x128 bf16) tile image

typedef __attribute__((ext_vector_type(4)))  float f32x4;
typedef __attribute__((ext_vector_type(16))) float f32x16;
typedef __attribute__((ext_vector_type(8)))  short s16x8;
typedef __attribute__((ext_vector_type(4)))  unsigned int u32x4;

__device__ __forceinline__ unsigned int cvtpk_bf16(float lo, float hi) {
  unsigned int r;
  asm("v_cvt_pk_bf16_f32 %0, %1, %2" : "=v"(r) : "v"(lo), "v"(hi));
  return r;
}
// x.hi32lanes = y.lo32lanes ; y.lo32lanes = x.hi32lanes_old
#define PLSWAP(x, y) asm volatile("v_permlane32_swap_b32 %0, %1" : "+v"(x), "+v"(y))

__device__ __forceinline__ unsigned int pk2(float lo, float hi) {
  unsigned short a = __builtin_bit_cast(unsigned short, __float2bfloat16(lo));
  unsigned short b = __builtin_bit_cast(unsigned short, __float2bfloat16(hi));
  return (unsigned int)a | ((unsigned int)b << 16);
}

#define AS1(p) ((const __attribute__((address_space(1))) void*)(p))
#define AS3(p) ((__attribute__((address_space(3))) void*)(p))

// ---------------- pass 1: K/V -> bf16 tiles in pre-swizzled LDS-image layout ----
// K image:  img[(r*256 + 2*d) ^ ((r&7)<<4)]  = bf16(K[r][d])   (r = k-row 0..63)
// Vt image: img[(d*128 + 2*k) ^ ((d&7)<<4)]  = bf16(V[k][d])   (d = 0..127, k = 0..63)
__global__ __launch_bounds__(256)
void prep_kv(const float* __restrict__ Kg, const float* __restrict__ Vg,
             char* __restrict__ wsK, char* __restrict__ wsV) {
  const int blk = blockIdx.x;          // b*32 + kt
  const int b   = blk >> 5;
  const int kt  = blk & 31;
  const int tid = threadIdx.x;
  const float* Ksrc = Kg + ((size_t)b * SQL + (size_t)kt * KBLK) * DH;
  const float* Vsrc = Vg + ((size_t)b * SQL + (size_t)kt * KBLK) * DH;
  char* Kdst = wsK + (size_t)blk * TILEB;
  char* Vdst = wsV + (size_t)blk * TILEB;

  {  // K: row-major bf16, swizzled
    const int q16 = tid & 15;          // 16B chunk (8 d-elems)
    const int r0  = tid >> 4;          // row 0..15
    #pragma unroll
    for (int it = 0; it < 4; ++it) {
      const int r = r0 + 16 * it;
      const float* src = Ksrc + (size_t)r * DH + 8 * q16;
      f32x4 a = *(const f32x4*)(src);
      f32x4 d = *(const f32x4*)(src + 4);
      u32x4 w;
      w[0] = pk2(a[0], a[1]); w[1] = pk2(a[2], a[3]);
      w[2] = pk2(d[0], d[1]); w[3] = pk2(d[2], d[3]);
      *(u32x4*)(Kdst + ((r * 256 + 16 * q16) ^ ((r & 7) << 4))) = w;
    }
  }
  {  // V: transposed Vt[d][k], swizzled (4x4 register transpose)
    const int kq = tid & 15;           // k0 = 4*kq
    const int dq = tid >> 4;           // d0 = 4*dq (+64 per it)
    #pragma unroll
    for (int it = 0; it < 2; ++it) {
      const int d0 = 4 * dq + 64 * it;
      f32x4 rv[4];
      #pragma unroll
      for (int j = 0; j < 4; ++j)
        rv[j] = *(const f32x4*)(Vsrc + (size_t)(4 * kq + j) * DH + d0);
      #pragma unroll
      for (int j2 = 0; j2 < 4; ++j2) {
        const int dd = d0 + j2;
        uint2 w = make_uint2(pk2(rv[0][j2], rv[1][j2]), pk2(rv[2][j2], rv[3][j2]));
        *(uint2*)(Vdst + ((dd * 128 + 8 * kq) ^ ((dd & 7) << 4))) = w;
      }
    }
  }
}

// ---------------- pass 2: flash attention, 32 q-rows/wave, global_load_lds ------
__global__ __launch_bounds__(256, 2)
void attn_fwd(const float* __restrict__ Qg, const char* __restrict__ wsK,
              const char* __restrict__ wsV, float* __restrict__ Og) {
  // K dbuf: 2 x 16KB @0; Vt dbuf: 2 x 16KB @32768. No P buffer (in-register).
  __shared__ __align__(16) char smem[65536];

  const int tid  = threadIdx.x;
  const int wid  = tid >> 6;
  const int lane = tid & 63;
  const int hi   = lane >> 5;
  const int c    = lane & 31;

  // complementary-pair decode: blocks 2c/2c+1 AND i/i+256 are heavy/light
  // complements (nt sums to 34 either way).
  const int i   = blockIdx.x;
  const int p   = i & 1;
  const int q3  = (i >> 1) & 7;
  const int b   = (i >> 4) & 31;
  const int qtb = (b & 16) ? (15 - q3) : q3;
  const int qt  = p ? qtb : (15 - qtb);
  const int qb  = qt * QBLK;
  const int nt  = 2 * qt + 2;

  const float* Qb = Qg + (size_t)b * SQL * DH;
  float* Ob = Og + (size_t)b * SQL * DH;
  const char* Ktiles = wsK + (size_t)b * NKT * TILEB;
  const char* Vtiles = wsV + (size_t)b * NKT * TILEB;

  const float qscale = 0.08838834764831845f * 1.4426950408889634f;  // 1/sqrt(128)*log2e

  // ---- Q fragments (B-operand of swapped QK^T, 32x32x16):
  // lane (hi,c) holds Q[q = qb+32*wid+c][d = 16*ds + 8*hi + j], j=0..7
  s16x8 qf[8];
  {
    const float* qr = Qb + (size_t)(qb + 32*wid + c) * DH + 8*hi;
    #pragma unroll
    for (int ds = 0; ds < 8; ++ds) {
      f32x4 a = *(const f32x4*)(qr + 16*ds);
      f32x4 d = *(const f32x4*)(qr + 16*ds + 4);
      u32x4 w;
      w[0] = pk2(a[0]*qscale, a[1]*qscale);
      w[1] = pk2(a[2]*qscale, a[3]*qscale);
      w[2] = pk2(d[0]*qscale, d[1]*qscale);
      w[3] = pk2(d[2]*qscale, d[3]*qscale);
      qf[ds] = __builtin_bit_cast(s16x8, w);
    }
  }

  f32x16 oacc[4];
  #pragma unroll
  for (int nb = 0; nb < 4; ++nb) oacc[nb] = (f32x16){0.f};
  float m_run = -1e30f, l_run = 0.f;

  const int qglob = qb + 32*wid + c;
  const int qhiw  = qb + 32*wid + 31;
  const int qlow  = qb + 32*wid;

  // stage tile t into LDS buf (t&1): 8 x global_load_lds (4 K + 4 Vt), 16B/lane
  auto STAGE = [&](int t) {
    const char* ks = Ktiles + (size_t)t * TILEB + tid * 16;
    const char* vs = Vtiles + (size_t)t * TILEB + tid * 16;
    char* kl = smem + (t & 1) * 16384 + wid * 1024;
    char* vl = smem + 32768 + (t & 1) * 16384 + wid * 1024;
    #pragma unroll
    for (int j = 0; j < 4; ++j) {
      __builtin_amdgcn_global_load_lds(AS1(ks + j * 4096), AS3(kl + j * 4096), 16, 0, 0);
      __builtin_amdgcn_global_load_lds(AS1(vs + j * 4096), AS3(vl + j * 4096), 16, 0, 0);
    }
  };

  STAGE(0);
  STAGE(1);   // nt >= 2 always

  for (int t = 0; t < nt; ++t) {
    // counted vmcnt: tile t's 8 loads are oldest; tile t+1's 8 stay in flight
    if (t == nt - 1) asm volatile("s_waitcnt vmcnt(0)" ::: "memory");
    else             asm volatile("s_waitcnt vmcnt(8)" ::: "memory");
    __builtin_amdgcn_s_barrier();
    __builtin_amdgcn_sched_barrier(0);

    const int kb = t * KBLK;
    const char* Kl = smem + (t & 1) * 16384;
    const char* Vl = smem + 32768 + (t & 1) * 16384;

    if (kb <= qhiw) {
      // ---- QK^T swapped: S^T[k][q], A = K from LDS, B = Q regs
      f32x16 sacc[2];
      sacc[0] = (f32x16){0.f};
      sacc[1] = (f32x16){0.f};
      __builtin_amdgcn_s_setprio(1);
      #pragma unroll
      for (int ds = 0; ds < 8; ++ds) {
        #pragma unroll
        for (int mb = 0; mb < 2; ++mb) {
          const int row = 32*mb + c;
          s16x8 kf = *(const s16x8*)(Kl + ((row*256 + 32*ds + 16*hi) ^ ((c & 7) << 4)));
          sacc[mb] = __builtin_amdgcn_mfma_f32_32x32x16_bf16(kf, qf[ds], sacc[mb], 0, 0, 0);
        }
      }
      __builtin_amdgcn_s_setprio(0);

      // ---- causal mask (diag-crossing tiles): lane holds S^T[k=kb+32mb+crow(r,hi)][q=c]
      if (kb + KBLK - 1 > qlow) {
        #pragma unroll
        for (int mb = 0; mb < 2; ++mb)
          #pragma unroll
          for (int r = 0; r < 16; ++r) {
            const int kk = kb + 32*mb + (r & 3) + 8*(r >> 2) + 4*hi;
            if (kk > qglob) sacc[mb][r] = -1e30f;
          }
      }

      // ---- row max (tree), q = c per lane; partner half at lane^32 (R6-verified)
      float mx[8];
      #pragma unroll
      for (int e = 0; e < 8; ++e)
        mx[e] = fmaxf(fmaxf(sacc[0][e], sacc[0][e+8]), fmaxf(sacc[1][e], sacc[1][e+8]));
      mx[0] = fmaxf(mx[0], mx[4]); mx[1] = fmaxf(mx[1], mx[5]);
      mx[2] = fmaxf(mx[2], mx[6]); mx[3] = fmaxf(mx[3], mx[7]);
      float tmax = fmaxf(fmaxf(mx[0], mx[1]), fmaxf(mx[2], mx[3]));
      tmax = fmaxf(tmax, __shfl_xor(tmax, 32));

      // ---- defer-max (T13): only rescale when max grew by > 8 (log2 units)
      if (!__all(tmax <= m_run + 8.0f)) {
        const float mnew  = fmaxf(m_run, tmax);
        const float alpha = exp2f(m_run - mnew);
        #pragma unroll
        for (int r = 0; r < 16; ++r) {
          float av = __shfl(alpha, (r & 3) + 8*(r >> 2) + 4*hi);
          #pragma unroll
          for (int nb = 0; nb < 4; ++nb) oacc[nb][r] *= av;
        }
        l_run *= alpha;
        m_run = mnew;
      }

      // ==== phase A: softmax of sacc[0] (k 0..31) -> pa0/pa1 -> PV ks=0,1
      float lsa = 0.f;
      unsigned int u0[8];
      #pragma unroll
      for (int w = 0; w < 8; ++w) {
        float p0 = exp2f(sacc[0][2*w]     - m_run);
        float p1 = exp2f(sacc[0][2*w + 1] - m_run);
        lsa += p0 + p1;
        u0[w] = cvtpk_bf16(p0, p1);
      }
      PLSWAP(u0[0], u0[2]); PLSWAP(u0[1], u0[3]);
      PLSWAP(u0[4], u0[6]); PLSWAP(u0[5], u0[7]);
      s16x8 pa0, pa1;
      { u32x4 w = {u0[0], u0[1], u0[2], u0[3]}; pa0 = __builtin_bit_cast(s16x8, w); }
      { u32x4 w = {u0[4], u0[5], u0[6], u0[7]}; pa1 = __builtin_bit_cast(s16x8, w); }
      __builtin_amdgcn_s_setprio(1);
      #pragma unroll
      for (int nb = 0; nb < 4; ++nb) {
        const int row = 32*nb + c;
        s16x8 vf0 = *(const s16x8*)(Vl + ((row*128 +  0 + 16*hi) ^ ((c & 7) << 4)));
        oacc[nb] = __builtin_amdgcn_mfma_f32_32x32x16_bf16(pa0, vf0, oacc[nb], 0, 0, 0);
        s16x8 vf1 = *(const s16x8*)(Vl + ((row*128 + 32 + 16*hi) ^ ((c & 7) << 4)));
        oacc[nb] = __builtin_amdgcn_mfma_f32_32x32x16_bf16(pa1, vf1, oacc[nb], 0, 0, 0);
      }
      __builtin_amdgcn_s_setprio(0);

      // ==== phase B: softmax of sacc[1] (k 32..63) overlaps phase-A MFMAs; PV ks=2,3
      float lsb = 0.f;
      unsigned int u1[8];
      #pragma unroll
      for (int w = 0; w < 8; ++w) {
        float p0 = exp2f(sacc[1][2*w]     - m_run);
        float p1 = exp2f(sacc[1][2*w + 1] - m_run);
        lsb += p0 + p1;
        u1[w] = cvtpk_bf16(p0, p1);
      }
      PLSWAP(u1[0], u1[2]); PLSWAP(u1[1], u1[3]);
      PLSWAP(u1[4], u1[6]); PLSWAP(u1[5], u1[7]);
      s16x8 pa2, pa3;
      { u32x4 w = {u1[0], u1[1], u1[2], u1[3]}; pa2 = __builtin_bit_cast(s16x8, w); }
      { u32x4 w = {u1[4], u1[5], u1[6], u1[7]}; pa3 = __builtin_bit_cast(s16x8, w); }
      __builtin_amdgcn_s_setprio(1);
      #pragma unroll
      for (int nb = 0; nb < 4; ++nb) {
        const int row = 32*nb + c;
        s16x8 vf2 = *(const s16x8*)(Vl + ((row*128 + 64 + 16*hi) ^ ((c & 7) << 4)));
        oacc[nb] = __builtin_amdgcn_mfma_f32_32x32x16_bf16(pa2, vf2, oacc[nb], 0, 0, 0);
        s16x8 vf3 = *(const s16x8*)(Vl + ((row*128 + 96 + 16*hi) ^ ((c & 7) << 4)));
        oacc[nb] = __builtin_amdgcn_mfma_f32_32x32x16_bf16(pa3, vf3, oacc[nb], 0, 0, 0);
      }
      __builtin_amdgcn_s_setprio(0);

      // ---- l update (R6-verified shfl_xor)
      float lsum = lsa + lsb;
      lsum += __shfl_xor(lsum, 32);
      l_run += lsum;
    }

    __builtin_amdgcn_s_barrier();     // all waves done reading buf (t&1)
    if (t + 2 < nt) STAGE(t + 2);     // refill it for tile t+2
  }

  // ---- epilogue: O rows q = crow(r,hi), cols d = 32nb + c
  const float linv = 1.0f / l_run;
  float* Orow = Ob + (size_t)(qb + 32*wid) * DH;
  #pragma unroll
  for (int r = 0; r < 16; ++r) {
    const int q = (r & 3) + 8*(r >> 2) + 4*hi;
    float lv = __shfl(linv, q);
    #pragma unroll
    for (int nb = 0; nb < 4; ++nb)
      Orow[(size_t)q * DH + 32*nb + c] = oacc[nb][r] * lv;
  }
}

extern "C" void kernel_launch(void* const* d_in, const int* in_sizes, int n_in,
                              void* d_out, int out_size, void* d_ws, size_t ws_size,
                              hipStream_t stream) {
  const float* Q = (const float*)d_in[0];
  const float* K = (const float*)d_in[1];
  const float* V = (const float*)d_in[2];
  // d_in[3]: causal mask, deterministic (triu k=1) -> synthesized in-kernel
  float* O = (float*)d_out;
  char* wsK = (char*)d_ws;                                   // 16 MB
  char* wsV = (char*)d_ws + (size_t)NB * NKT * TILEB;        // 16 MB

  prep_kv<<<dim3(NB * NKT), dim3(256), 0, stream>>>(K, V, wsK, wsV);
  attn_fwd<<<dim3(NB * (SQL / QBLK)), dim3(256), 0, stream>>>(Q, wsK, wsV, O);
}

// Round 10
// 89.978 us; speedup vs baseline: 2.1460x; 1.0385x over previous
//
#include <hip/hip_runtime.h>
#include <hip/hip_bf16.h>

#define NB   32
#define SQL  2048
#define DH   128
#define QBLK 128
#define KBLK 64
#define NKT  (SQL / KBLK)      // 32 k-tiles per batch
#define TILEB 16384            // bytes per (64x128 bf16) tile image

typedef __attribute__((ext_vector_type(4)))  float f32x4;
typedef __attribute__((ext_vector_type(16))) float f32x16;
typedef __attribute__((ext_vector_type(8)))  short s16x8;
typedef __attribute__((ext_vector_type(4)))  unsigned int u32x4;

__device__ __forceinline__ unsigned int cvtpk_bf16(float lo, float hi) {
  unsigned int r;
  asm("v_cvt_pk_bf16_f32 %0, %1, %2" : "=v"(r) : "v"(lo), "v"(hi));
  return r;
}
// x.hi32lanes = y.lo32lanes ; y.lo32lanes = x.hi32lanes_old
#define PLSWAP(x, y) asm volatile("v_permlane32_swap_b32 %0, %1" : "+v"(x), "+v"(y))

__device__ __forceinline__ unsigned int pk2(float lo, float hi) {
  unsigned short a = __builtin_bit_cast(unsigned short, __float2bfloat16(lo));
  unsigned short b = __builtin_bit_cast(unsigned short, __float2bfloat16(hi));
  return (unsigned int)a | ((unsigned int)b << 16);
}

#define AS1(p) ((const __attribute__((address_space(1))) void*)(p))
#define AS3(p) ((__attribute__((address_space(3))) void*)(p))

// ---------------- pass 1: K/V -> bf16 tiles in pre-swizzled LDS-image layout ----
// K image:  img[(r*256 + 2*d) ^ ((r&7)<<4)]  = bf16(K[r][d])   (r = k-row 0..63)
// Vt image: img[(d*128 + 2*k) ^ ((d&7)<<4)]  = bf16(V[k][d])   (d = 0..127, k = 0..63)
__global__ __launch_bounds__(256)
void prep_kv(const float* __restrict__ Kg, const float* __restrict__ Vg,
             char* __restrict__ wsK, char* __restrict__ wsV) {
  const int blk = blockIdx.x;          // b*32 + kt
  const int b   = blk >> 5;
  const int kt  = blk & 31;
  const int tid = threadIdx.x;
  const float* Ksrc = Kg + ((size_t)b * SQL + (size_t)kt * KBLK) * DH;
  const float* Vsrc = Vg + ((size_t)b * SQL + (size_t)kt * KBLK) * DH;
  char* Kdst = wsK + (size_t)blk * TILEB;
  char* Vdst = wsV + (size_t)blk * TILEB;

  {  // K: row-major bf16, swizzled
    const int q16 = tid & 15;          // 16B chunk (8 d-elems)
    const int r0  = tid >> 4;          // row 0..15
    #pragma unroll
    for (int it = 0; it < 4; ++it) {
      const int r = r0 + 16 * it;
      const float* src = Ksrc + (size_t)r * DH + 8 * q16;
      f32x4 a = *(const f32x4*)(src);
      f32x4 d = *(const f32x4*)(src + 4);
      u32x4 w;
      w[0] = pk2(a[0], a[1]); w[1] = pk2(a[2], a[3]);
      w[2] = pk2(d[0], d[1]); w[3] = pk2(d[2], d[3]);
      *(u32x4*)(Kdst + ((r * 256 + 16 * q16) ^ ((r & 7) << 4))) = w;
    }
  }
  {  // V: transposed Vt[d][k], swizzled (4x4 register transpose)
    const int kq = tid & 15;           // k0 = 4*kq
    const int dq = tid >> 4;           // d0 = 4*dq (+64 per it)
    #pragma unroll
    for (int it = 0; it < 2; ++it) {
      const int d0 = 4 * dq + 64 * it;
      f32x4 rv[4];
      #pragma unroll
      for (int j = 0; j < 4; ++j)
        rv[j] = *(const f32x4*)(Vsrc + (size_t)(4 * kq + j) * DH + d0);
      #pragma unroll
      for (int j2 = 0; j2 < 4; ++j2) {
        const int dd = d0 + j2;
        uint2 w = make_uint2(pk2(rv[0][j2], rv[1][j2]), pk2(rv[2][j2], rv[3][j2]));
        *(uint2*)(Vdst + ((dd * 128 + 8 * kq) ^ ((dd & 7) << 4))) = w;
      }
    }
  }
}

// ---------------- pass 2: flash attention, 32 q-rows/wave, global_load_lds ------
__global__ __launch_bounds__(256, 2)
void attn_fwd(const float* __restrict__ Qg, const char* __restrict__ wsK,
              const char* __restrict__ wsV, float* __restrict__ Og) {
  // K dbuf: 2 x 16KB @0; Vt dbuf: 2 x 16KB @32768. No P buffer (in-register).
  __shared__ __align__(16) char smem[65536];

  const int tid  = threadIdx.x;
  const int wid  = tid >> 6;
  const int lane = tid & 63;
  const int hi   = lane >> 5;
  const int c    = lane & 31;

  // XCD-affine decode (T1 adapted): under round-robin workgroup->XCD dispatch,
  // XCD x = i&7 serves batches {x, x+8, x+16, x+24} only -> per-XCD KV working
  // set is L2-sized. CU-mate pairing j <-> j+32 gets complementary qt
  // (qrow vs 15-qrow, nt sums to 34) for static load balance.
  const int i    = blockIdx.x;         // 0..511
  const int x    = i & 7;              // XCD slot
  const int j    = i >> 3;             // 0..63 within XCD
  const int b    = x + 8 * (j & 3);    // batch (4 per XCD)
  const int qrow = j >> 2;             // 0..15
  const int qt   = (qrow < 8) ? qrow : (23 - qrow);
  const int qb   = qt * QBLK;
  const int nt   = 2 * qt + 2;

  const float* Qb = Qg + (size_t)b * SQL * DH;
  float* Ob = Og + (size_t)b * SQL * DH;
  const char* Ktiles = wsK + (size_t)b * NKT * TILEB;
  const char* Vtiles = wsV + (size_t)b * NKT * TILEB;

  const float qscale = 0.08838834764831845f * 1.4426950408889634f;  // 1/sqrt(128)*log2e

  // ---- Q fragments (B-operand of swapped QK^T, 32x32x16):
  // lane (hi,c) holds Q[q = qb+32*wid+c][d = 16*ds + 8*hi + j], j=0..7
  s16x8 qf[8];
  {
    const float* qr = Qb + (size_t)(qb + 32*wid + c) * DH + 8*hi;
    #pragma unroll
    for (int ds = 0; ds < 8; ++ds) {
      f32x4 a = *(const f32x4*)(qr + 16*ds);
      f32x4 d = *(const f32x4*)(qr + 16*ds + 4);
      u32x4 w;
      w[0] = pk2(a[0]*qscale, a[1]*qscale);
      w[1] = pk2(a[2]*qscale, a[3]*qscale);
      w[2] = pk2(d[0]*qscale, d[1]*qscale);
      w[3] = pk2(d[2]*qscale, d[3]*qscale);
      qf[ds] = __builtin_bit_cast(s16x8, w);
    }
  }

  f32x16 oacc[4];
  #pragma unroll
  for (int nb = 0; nb < 4; ++nb) oacc[nb] = (f32x16){0.f};
  float m_run = -1e30f, l_run = 0.f;

  const int qglob = qb + 32*wid + c;
  const int qhiw  = qb + 32*wid + 31;
  const int qlow  = qb + 32*wid;

  // stage tile t into LDS buf (t&1): 8 x global_load_lds (4 K + 4 Vt), 16B/lane
  auto STAGE = [&](int t) {
    const char* ks = Ktiles + (size_t)t * TILEB + tid * 16;
    const char* vs = Vtiles + (size_t)t * TILEB + tid * 16;
    char* kl = smem + (t & 1) * 16384 + wid * 1024;
    char* vl = smem + 32768 + (t & 1) * 16384 + wid * 1024;
    #pragma unroll
    for (int jj = 0; jj < 4; ++jj) {
      __builtin_amdgcn_global_load_lds(AS1(ks + jj * 4096), AS3(kl + jj * 4096), 16, 0, 0);
      __builtin_amdgcn_global_load_lds(AS1(vs + jj * 4096), AS3(vl + jj * 4096), 16, 0, 0);
    }
  };

  STAGE(0);
  STAGE(1);   // nt >= 2 always

  for (int t = 0; t < nt; ++t) {
    // counted vmcnt: tile t's 8 loads are oldest; tile t+1's 8 stay in flight
    if (t == nt - 1) asm volatile("s_waitcnt vmcnt(0)" ::: "memory");
    else             asm volatile("s_waitcnt vmcnt(8)" ::: "memory");
    __builtin_amdgcn_s_barrier();
    __builtin_amdgcn_sched_barrier(0);

    const int kb = t * KBLK;
    const char* Kl = smem + (t & 1) * 16384;
    const char* Vl = smem + 32768 + (t & 1) * 16384;

    if (kb <= qhiw) {
      // ---- QK^T swapped: S^T[k][q], A = K from LDS, B = Q regs
      f32x16 sacc[2];
      sacc[0] = (f32x16){0.f};
      sacc[1] = (f32x16){0.f};
      __builtin_amdgcn_s_setprio(1);
      #pragma unroll
      for (int ds = 0; ds < 8; ++ds) {
        #pragma unroll
        for (int mb = 0; mb < 2; ++mb) {
          const int row = 32*mb + c;
          s16x8 kf = *(const s16x8*)(Kl + ((row*256 + 32*ds + 16*hi) ^ ((c & 7) << 4)));
          sacc[mb] = __builtin_amdgcn_mfma_f32_32x32x16_bf16(kf, qf[ds], sacc[mb], 0, 0, 0);
        }
      }
      __builtin_amdgcn_s_setprio(0);

      // ---- causal mask (diag-crossing tiles): lane holds S^T[k=kb+32mb+crow(r,hi)][q=c]
      if (kb + KBLK - 1 > qlow) {
        #pragma unroll
        for (int mb = 0; mb < 2; ++mb)
          #pragma unroll
          for (int r = 0; r < 16; ++r) {
            const int kk = kb + 32*mb + (r & 3) + 8*(r >> 2) + 4*hi;
            if (kk > qglob) sacc[mb][r] = -1e30f;
          }
      }

      // ---- row max (tree), q = c per lane; partner half at lane^32
      float mx[8];
      #pragma unroll
      for (int e = 0; e < 8; ++e)
        mx[e] = fmaxf(fmaxf(sacc[0][e], sacc[0][e+8]), fmaxf(sacc[1][e], sacc[1][e+8]));
      mx[0] = fmaxf(mx[0], mx[4]); mx[1] = fmaxf(mx[1], mx[5]);
      mx[2] = fmaxf(mx[2], mx[6]); mx[3] = fmaxf(mx[3], mx[7]);
      float tmax = fmaxf(fmaxf(mx[0], mx[1]), fmaxf(mx[2], mx[3]));
      tmax = fmaxf(tmax, __shfl_xor(tmax, 32));

      // ---- defer-max (T13): only rescale when max grew by > 8 (log2 units)
      if (!__all(tmax <= m_run + 8.0f)) {
        const float mnew  = fmaxf(m_run, tmax);
        const float alpha = exp2f(m_run - mnew);
        #pragma unroll
        for (int r = 0; r < 16; ++r) {
          float av = __shfl(alpha, (r & 3) + 8*(r >> 2) + 4*hi);
          #pragma unroll
          for (int nb = 0; nb < 4; ++nb) oacc[nb][r] *= av;
        }
        l_run *= alpha;
        m_run = mnew;
      }

      // ---- p = exp2(s - m) interleaved with pack
      float lsa = 0.f, lsb = 0.f;
      unsigned int u0[8], u1[8];
      #pragma unroll
      for (int w = 0; w < 8; ++w) {
        float p0 = exp2f(sacc[0][2*w]     - m_run);
        float p1 = exp2f(sacc[0][2*w + 1] - m_run);
        lsa += p0 + p1;
        u0[w] = cvtpk_bf16(p0, p1);
      }
      #pragma unroll
      for (int w = 0; w < 8; ++w) {
        float p0 = exp2f(sacc[1][2*w]     - m_run);
        float p1 = exp2f(sacc[1][2*w + 1] - m_run);
        lsb += p0 + p1;
        u1[w] = cvtpk_bf16(p0, p1);
      }
      float lsum = lsa + lsb;
      lsum += __shfl_xor(lsum, 32);
      l_run += lsum;

      // ---- in-register P -> PV A-frags via permlane32_swap (T12, HW-verified)
      PLSWAP(u0[0], u0[2]); PLSWAP(u0[1], u0[3]);
      PLSWAP(u0[4], u0[6]); PLSWAP(u0[5], u0[7]);
      PLSWAP(u1[0], u1[2]); PLSWAP(u1[1], u1[3]);
      PLSWAP(u1[4], u1[6]); PLSWAP(u1[5], u1[7]);
      s16x8 pa[4];
      { u32x4 w = {u0[0], u0[1], u0[2], u0[3]}; pa[0] = __builtin_bit_cast(s16x8, w); }
      { u32x4 w = {u0[4], u0[5], u0[6], u0[7]}; pa[1] = __builtin_bit_cast(s16x8, w); }
      { u32x4 w = {u1[0], u1[1], u1[2], u1[3]}; pa[2] = __builtin_bit_cast(s16x8, w); }
      { u32x4 w = {u1[4], u1[5], u1[6], u1[7]}; pa[3] = __builtin_bit_cast(s16x8, w); }

      // ---- PV: O[q][d] += P[q][k] Vt[d][k]^T  (A = P regs, B = V from LDS)
      __builtin_amdgcn_s_setprio(1);
      #pragma unroll
      for (int nb = 0; nb < 4; ++nb) {
        #pragma unroll
        for (int ks = 0; ks < 4; ++ks) {
          const int row = 32*nb + c;
          s16x8 vf = *(const s16x8*)(Vl + ((row*128 + 32*ks + 16*hi) ^ ((c & 7) << 4)));
          oacc[nb] = __builtin_amdgcn_mfma_f32_32x32x16_bf16(pa[ks], vf, oacc[nb], 0, 0, 0);
        }
      }
      __builtin_amdgcn_s_setprio(0);
    }

    __builtin_amdgcn_s_barrier();     // all waves done reading buf (t&1)
    if (t + 2 < nt) STAGE(t + 2);     // refill it for tile t+2
  }

  // ---- epilogue: O rows q = crow(r,hi), cols d = 32nb + c
  const float linv = 1.0f / l_run;
  float* Orow = Ob + (size_t)(qb + 32*wid) * DH;
  #pragma unroll
  for (int r = 0; r < 16; ++r) {
    const int q = (r & 3) + 8*(r >> 2) + 4*hi;
    float lv = __shfl(linv, q);
    #pragma unroll
    for (int nb = 0; nb < 4; ++nb)
      Orow[(size_t)q * DH + 32*nb + c] = oacc[nb][r] * lv;
  }
}

extern "C" void kernel_launch(void* const* d_in, const int* in_sizes, int n_in,
                              void* d_out, int out_size, void* d_ws, size_t ws_size,
                              hipStream_t stream) {
  const float* Q = (const float*)d_in[0];
  const float* K = (const float*)d_in[1];
  const float* V = (const float*)d_in[2];
  // d_in[3]: causal mask, deterministic (triu k=1) -> synthesized in-kernel
  float* O = (float*)d_out;
  char* wsK = (char*)d_ws;                                   // 16 MB
  char* wsV = (char*)d_ws + (size_t)NB * NKT * TILEB;        // 16 MB

  prep_kv<<<dim3(NB * NKT), dim3(256), 0, stream>>>(K, V, wsK, wsV);
  attn_fwd<<<dim3(NB * (SQL / QBLK)), dim3(256), 0, stream>>>(Q, wsK, wsV, O);
}

// Round 11
// 87.946 us; speedup vs baseline: 2.1956x; 1.0231x over previous
//
#include <hip/hip_runtime.h>
#include <hip/hip_bf16.h>

#define NB   32
#define SQL  2048
#define DH   128
#define QBLK 128
#define KBLK 64
#define NKT  (SQL / KBLK)      // 32 k-tiles per batch
#define TILEB 16384            // bytes per (64x128 bf16) tile image

typedef __attribute__((ext_vector_type(4)))  float f32x4;
typedef __attribute__((ext_vector_type(16))) float f32x16;
typedef __attribute__((ext_vector_type(8)))  short s16x8;
typedef __attribute__((ext_vector_type(4)))  unsigned int u32x4;

__device__ __forceinline__ unsigned int cvtpk_bf16(float lo, float hi) {
  unsigned int r;
  asm("v_cvt_pk_bf16_f32 %0, %1, %2" : "=v"(r) : "v"(lo), "v"(hi));
  return r;
}
// x.hi32lanes = y.lo32lanes ; y.lo32lanes = x.hi32lanes_old
#define PLSWAP(x, y) asm volatile("v_permlane32_swap_b32 %0, %1" : "+v"(x), "+v"(y))

__device__ __forceinline__ unsigned int pk2(float lo, float hi) {
  unsigned short a = __builtin_bit_cast(unsigned short, __float2bfloat16(lo));
  unsigned short b = __builtin_bit_cast(unsigned short, __float2bfloat16(hi));
  return (unsigned int)a | ((unsigned int)b << 16);
}

#define AS1(p) ((const __attribute__((address_space(1))) void*)(p))
#define AS3(p) ((__attribute__((address_space(3))) void*)(p))

// ---------------- pass 1: K/V -> bf16 tiles in pre-swizzled LDS-image layout ----
// K image:  img[(r*256 + 2*d) ^ ((r&7)<<4)]  = bf16(K[r][d])   (r = k-row 0..63)
// Vt image: img[(d*128 + 2*k) ^ ((d&7)<<4)]  = bf16(V[k][d])   (d = 0..127, k = 0..63)
__global__ __launch_bounds__(256)
void prep_kv(const float* __restrict__ Kg, const float* __restrict__ Vg,
             char* __restrict__ wsK, char* __restrict__ wsV) {
  const int blk = blockIdx.x;          // b*32 + kt
  const int b   = blk >> 5;
  const int kt  = blk & 31;
  const int tid = threadIdx.x;
  const float* Ksrc = Kg + ((size_t)b * SQL + (size_t)kt * KBLK) * DH;
  const float* Vsrc = Vg + ((size_t)b * SQL + (size_t)kt * KBLK) * DH;
  char* Kdst = wsK + (size_t)blk * TILEB;
  char* Vdst = wsV + (size_t)blk * TILEB;

  {  // K: row-major bf16, swizzled
    const int q16 = tid & 15;          // 16B chunk (8 d-elems)
    const int r0  = tid >> 4;          // row 0..15
    #pragma unroll
    for (int it = 0; it < 4; ++it) {
      const int r = r0 + 16 * it;
      const float* src = Ksrc + (size_t)r * DH + 8 * q16;
      f32x4 a = *(const f32x4*)(src);
      f32x4 d = *(const f32x4*)(src + 4);
      u32x4 w;
      w[0] = pk2(a[0], a[1]); w[1] = pk2(a[2], a[3]);
      w[2] = pk2(d[0], d[1]); w[3] = pk2(d[2], d[3]);
      *(u32x4*)(Kdst + ((r * 256 + 16 * q16) ^ ((r & 7) << 4))) = w;
    }
  }
  {  // V: transposed Vt[d][k], swizzled (4x4 register transpose)
    const int kq = tid & 15;           // k0 = 4*kq
    const int dq = tid >> 4;           // d0 = 4*dq (+64 per it)
    #pragma unroll
    for (int it = 0; it < 2; ++it) {
      const int d0 = 4 * dq + 64 * it;
      f32x4 rv[4];
      #pragma unroll
      for (int j = 0; j < 4; ++j)
        rv[j] = *(const f32x4*)(Vsrc + (size_t)(4 * kq + j) * DH + d0);
      #pragma unroll
      for (int j2 = 0; j2 < 4; ++j2) {
        const int dd = d0 + j2;
        uint2 w = make_uint2(pk2(rv[0][j2], rv[1][j2]), pk2(rv[2][j2], rv[3][j2]));
        *(uint2*)(Vdst + ((dd * 128 + 8 * kq) ^ ((dd & 7) << 4))) = w;
      }
    }
  }
}

// ---------------- pass 2: flash attention, 32 q-rows/wave, global_load_lds ------
__global__ __launch_bounds__(256, 2)
void attn_fwd(const float* __restrict__ Qg, const char* __restrict__ wsK,
              const char* __restrict__ wsV, float* __restrict__ Og) {
  // K dbuf: 2 x 16KB @0; Vt dbuf: 2 x 16KB @32768. No P buffer (in-register).
  __shared__ __align__(16) char smem[65536];

  const int tid  = threadIdx.x;
  const int wid  = tid >> 6;
  const int lane = tid & 63;
  const int hi   = lane >> 5;
  const int c    = lane & 31;

  // complementary-pair decode: blocks 2c/2c+1 AND i/i+256 are heavy/light
  // complements (nt sums to 34 either way).
  const int i   = blockIdx.x;
  const int p   = i & 1;
  const int q3  = (i >> 1) & 7;
  const int b   = (i >> 4) & 31;
  const int qtb = (b & 16) ? (15 - q3) : q3;
  const int qt  = p ? qtb : (15 - qtb);
  const int qb  = qt * QBLK;
  const int nt  = 2 * qt + 2;

  const float* Qb = Qg + (size_t)b * SQL * DH;
  float* Ob = Og + (size_t)b * SQL * DH;
  const char* Ktiles = wsK + (size_t)b * NKT * TILEB;
  const char* Vtiles = wsV + (size_t)b * NKT * TILEB;

  const float qscale = 0.08838834764831845f * 1.4426950408889634f;  // 1/sqrt(128)*log2e

  // ---- Q fragments (B-operand of swapped QK^T, 32x32x16):
  // lane (hi,c) holds Q[q = qb+32*wid+c][d = 16*ds + 8*hi + j], j=0..7
  s16x8 qf[8];
  {
    const float* qr = Qb + (size_t)(qb + 32*wid + c) * DH + 8*hi;
    #pragma unroll
    for (int ds = 0; ds < 8; ++ds) {
      f32x4 a = *(const f32x4*)(qr + 16*ds);
      f32x4 d = *(const f32x4*)(qr + 16*ds + 4);
      u32x4 w;
      w[0] = pk2(a[0]*qscale, a[1]*qscale);
      w[1] = pk2(a[2]*qscale, a[3]*qscale);
      w[2] = pk2(d[0]*qscale, d[1]*qscale);
      w[3] = pk2(d[2]*qscale, d[3]*qscale);
      qf[ds] = __builtin_bit_cast(s16x8, w);
    }
  }

  f32x16 oacc[4];
  #pragma unroll
  for (int nb = 0; nb < 4; ++nb) oacc[nb] = (f32x16){0.f};
  // l_run is a PER-HALF partial sum (lane c holds k<32-half, lane c+32 the other);
  // halves are combined once in the epilogue. alpha is row-uniform so rescale
  // of the partial is exact.
  float m_run = -1e30f, l_run = 0.f;

  const int qglob = qb + 32*wid + c;
  const int qhiw  = qb + 32*wid + 31;
  const int qlow  = qb + 32*wid;

  // stage tile t into LDS buf (t&1): 8 x global_load_lds (4 K + 4 Vt), 16B/lane
  auto STAGE = [&](int t) {
    const char* ks = Ktiles + (size_t)t * TILEB + tid * 16;
    const char* vs = Vtiles + (size_t)t * TILEB + tid * 16;
    char* kl = smem + (t & 1) * 16384 + wid * 1024;
    char* vl = smem + 32768 + (t & 1) * 16384 + wid * 1024;
    #pragma unroll
    for (int jj = 0; jj < 4; ++jj) {
      __builtin_amdgcn_global_load_lds(AS1(ks + jj * 4096), AS3(kl + jj * 4096), 16, 0, 0);
      __builtin_amdgcn_global_load_lds(AS1(vs + jj * 4096), AS3(vl + jj * 4096), 16, 0, 0);
    }
  };

  STAGE(0);
  STAGE(1);   // nt >= 2 always

  for (int t = 0; t < nt; ++t) {
    // counted vmcnt: tile t's 8 loads are oldest; tile t+1's 8 stay in flight
    if (t == nt - 1) asm volatile("s_waitcnt vmcnt(0)" ::: "memory");
    else             asm volatile("s_waitcnt vmcnt(8)" ::: "memory");
    __builtin_amdgcn_s_barrier();
    __builtin_amdgcn_sched_barrier(0);

    const int kb = t * KBLK;
    const char* Kl = smem + (t & 1) * 16384;
    const char* Vl = smem + 32768 + (t & 1) * 16384;

    if (kb <= qhiw) {
      // ---- QK^T swapped: S^T[k][q], A = K from LDS, B = Q regs
      f32x16 sacc[2];
      sacc[0] = (f32x16){0.f};
      sacc[1] = (f32x16){0.f};
      __builtin_amdgcn_s_setprio(1);
      #pragma unroll
      for (int ds = 0; ds < 8; ++ds) {
        #pragma unroll
        for (int mb = 0; mb < 2; ++mb) {
          const int row = 32*mb + c;
          s16x8 kf = *(const s16x8*)(Kl + ((row*256 + 32*ds + 16*hi) ^ ((c & 7) << 4)));
          sacc[mb] = __builtin_amdgcn_mfma_f32_32x32x16_bf16(kf, qf[ds], sacc[mb], 0, 0, 0);
        }
      }
      __builtin_amdgcn_s_setprio(0);

      // ---- causal mask (diag-crossing tiles): lane holds S^T[k=kb+32mb+crow(r,hi)][q=c]
      if (kb + KBLK - 1 > qlow) {
        #pragma unroll
        for (int mb = 0; mb < 2; ++mb)
          #pragma unroll
          for (int r = 0; r < 16; ++r) {
            const int kk = kb + 32*mb + (r & 3) + 8*(r >> 2) + 4*hi;
            if (kk > qglob) sacc[mb][r] = -1e30f;
          }
      }

      // ---- per-half row max (tree); NO cross-half shuffle on the fast path.
      // __all over 64 lanes of the half-max condition == R6's full-max condition.
      float mx[8];
      #pragma unroll
      for (int e = 0; e < 8; ++e)
        mx[e] = fmaxf(fmaxf(sacc[0][e], sacc[0][e+8]), fmaxf(sacc[1][e], sacc[1][e+8]));
      mx[0] = fmaxf(mx[0], mx[4]); mx[1] = fmaxf(mx[1], mx[5]);
      mx[2] = fmaxf(mx[2], mx[6]); mx[3] = fmaxf(mx[3], mx[7]);
      const float tmax = fmaxf(fmaxf(mx[0], mx[1]), fmaxf(mx[2], mx[3]));

      // ---- defer-max (T13): rescale only when some row's max grew by > 8
      if (!__all(tmax <= m_run + 8.0f)) {
        float tfull = fmaxf(tmax, __shfl_xor(tmax, 32));   // shuffle only on the rare path
        const float mnew  = fmaxf(m_run, tfull);
        const float alpha = exp2f(m_run - mnew);
        #pragma unroll
        for (int r = 0; r < 16; ++r) {
          float av = __shfl(alpha, (r & 3) + 8*(r >> 2) + 4*hi);
          #pragma unroll
          for (int nb = 0; nb < 4; ++nb) oacc[nb][r] *= av;
        }
        l_run *= alpha;        // per-half partial scales exactly (alpha row-uniform)
        m_run = mnew;
      }

      // ---- p = exp2(s - m) interleaved with pack; l accumulated per-half only
      float lsa = 0.f, lsb = 0.f;
      unsigned int u0[8], u1[8];
      #pragma unroll
      for (int w = 0; w < 8; ++w) {
        float p0 = exp2f(sacc[0][2*w]     - m_run);
        float p1 = exp2f(sacc[0][2*w + 1] - m_run);
        lsa += p0 + p1;
        u0[w] = cvtpk_bf16(p0, p1);
      }
      #pragma unroll
      for (int w = 0; w < 8; ++w) {
        float p0 = exp2f(sacc[1][2*w]     - m_run);
        float p1 = exp2f(sacc[1][2*w + 1] - m_run);
        lsb += p0 + p1;
        u1[w] = cvtpk_bf16(p0, p1);
      }
      l_run += lsa + lsb;      // NO per-tile cross-half shuffle (epilogue combines)

      // ---- in-register P -> PV A-frags via permlane32_swap (T12, HW-verified)
      PLSWAP(u0[0], u0[2]); PLSWAP(u0[1], u0[3]);
      PLSWAP(u0[4], u0[6]); PLSWAP(u0[5], u0[7]);
      PLSWAP(u1[0], u1[2]); PLSWAP(u1[1], u1[3]);
      PLSWAP(u1[4], u1[6]); PLSWAP(u1[5], u1[7]);
      s16x8 pa[4];
      { u32x4 w = {u0[0], u0[1], u0[2], u0[3]}; pa[0] = __builtin_bit_cast(s16x8, w); }
      { u32x4 w = {u0[4], u0[5], u0[6], u0[7]}; pa[1] = __builtin_bit_cast(s16x8, w); }
      { u32x4 w = {u1[0], u1[1], u1[2], u1[3]}; pa[2] = __builtin_bit_cast(s16x8, w); }
      { u32x4 w = {u1[4], u1[5], u1[6], u1[7]}; pa[3] = __builtin_bit_cast(s16x8, w); }

      // ---- PV: O[q][d] += P[q][k] Vt[d][k]^T  (A = P regs, B = V from LDS)
      __builtin_amdgcn_s_setprio(1);
      #pragma unroll
      for (int nb = 0; nb < 4; ++nb) {
        #pragma unroll
        for (int ks = 0; ks < 4; ++ks) {
          const int row = 32*nb + c;
          s16x8 vf = *(const s16x8*)(Vl + ((row*128 + 32*ks + 16*hi) ^ ((c & 7) << 4)));
          oacc[nb] = __builtin_amdgcn_mfma_f32_32x32x16_bf16(pa[ks], vf, oacc[nb], 0, 0, 0);
        }
      }
      __builtin_amdgcn_s_setprio(0);
    }

    __builtin_amdgcn_s_barrier();     // all waves done reading buf (t&1)
    if (t + 2 < nt) STAGE(t + 2);     // refill it for tile t+2
  }

  // ---- epilogue: combine l halves ONCE, then store O
  const float l_tot = l_run + __shfl_xor(l_run, 32);
  const float linv  = 1.0f / l_tot;
  float* Orow = Ob + (size_t)(qb + 32*wid) * DH;
  #pragma unroll
  for (int r = 0; r < 16; ++r) {
    const int q = (r & 3) + 8*(r >> 2) + 4*hi;
    float lv = __shfl(linv, q);
    #pragma unroll
    for (int nb = 0; nb < 4; ++nb)
      Orow[(size_t)q * DH + 32*nb + c] = oacc[nb][r] * lv;
  }
}

extern "C" void kernel_launch(void* const* d_in, const int* in_sizes, int n_in,
                              void* d_out, int out_size, void* d_ws, size_t ws_size,
                              hipStream_t stream) {
  const float* Q = (const float*)d_in[0];
  const float* K = (const float*)d_in[1];
  const float* V = (const float*)d_in[2];
  // d_in[3]: causal mask, deterministic (triu k=1) -> synthesized in-kernel
  float* O = (float*)d_out;
  char* wsK = (char*)d_ws;                                   // 16 MB
  char* wsV = (char*)d_ws + (size_t)NB * NKT * TILEB;        // 16 MB

  prep_kv<<<dim3(NB * NKT), dim3(256), 0, stream>>>(K, V, wsK, wsV);
  attn_fwd<<<dim3(NB * (SQL / QBLK)), dim3(256), 0, stream>>>(Q, wsK, wsV, O);
}

// Round 12
// 87.327 us; speedup vs baseline: 2.2111x; 1.0071x over previous
//
#include <hip/hip_runtime.h>
#include <hip/hip_bf16.h>

#define NB   32
#define SQL  2048
#define DH   128
#define QBLK 128
#define KBLK 64
#define NKT  (SQL / KBLK)      // 32 k-tiles per batch
#define TILEB 16384            // bytes per (64x128 bf16) tile image

typedef __attribute__((ext_vector_type(4)))  float f32x4;
typedef __attribute__((ext_vector_type(16))) float f32x16;
typedef __attribute__((ext_vector_type(8)))  short s16x8;
typedef __attribute__((ext_vector_type(4)))  unsigned int u32x4;

__device__ __forceinline__ unsigned int cvtpk_bf16(float lo, float hi) {
  unsigned int r;
  asm("v_cvt_pk_bf16_f32 %0, %1, %2" : "=v"(r) : "v"(lo), "v"(hi));
  return r;
}
// x.hi32lanes = y.lo32lanes ; y.lo32lanes = x.hi32lanes_old
#define PLSWAP(x, y) asm volatile("v_permlane32_swap_b32 %0, %1" : "+v"(x), "+v"(y))

__device__ __forceinline__ unsigned int pk2(float lo, float hi) {
  unsigned short a = __builtin_bit_cast(unsigned short, __float2bfloat16(lo));
  unsigned short b = __builtin_bit_cast(unsigned short, __float2bfloat16(hi));
  return (unsigned int)a | ((unsigned int)b << 16);
}

#define AS1(p) ((const __attribute__((address_space(1))) void*)(p))
#define AS3(p) ((__attribute__((address_space(3))) void*)(p))

// ---------------- pass 1: K/V -> bf16 tiles in pre-swizzled LDS-image layout ----
__global__ __launch_bounds__(256)
void prep_kv(const float* __restrict__ Kg, const float* __restrict__ Vg,
             char* __restrict__ wsK, char* __restrict__ wsV) {
  const int blk = blockIdx.x;          // b*32 + kt
  const int b   = blk >> 5;
  const int kt  = blk & 31;
  const int tid = threadIdx.x;
  const float* Ksrc = Kg + ((size_t)b * SQL + (size_t)kt * KBLK) * DH;
  const float* Vsrc = Vg + ((size_t)b * SQL + (size_t)kt * KBLK) * DH;
  char* Kdst = wsK + (size_t)blk * TILEB;
  char* Vdst = wsV + (size_t)blk * TILEB;

  {  // K: row-major bf16, swizzled
    const int q16 = tid & 15;
    const int r0  = tid >> 4;
    #pragma unroll
    for (int it = 0; it < 4; ++it) {
      const int r = r0 + 16 * it;
      const float* src = Ksrc + (size_t)r * DH + 8 * q16;
      f32x4 a = *(const f32x4*)(src);
      f32x4 d = *(const f32x4*)(src + 4);
      u32x4 w;
      w[0] = pk2(a[0], a[1]); w[1] = pk2(a[2], a[3]);
      w[2] = pk2(d[0], d[1]); w[3] = pk2(d[2], d[3]);
      *(u32x4*)(Kdst + ((r * 256 + 16 * q16) ^ ((r & 7) << 4))) = w;
    }
  }
  {  // V: transposed Vt[d][k], swizzled
    const int kq = tid & 15;
    const int dq = tid >> 4;
    #pragma unroll
    for (int it = 0; it < 2; ++it) {
      const int d0 = 4 * dq + 64 * it;
      f32x4 rv[4];
      #pragma unroll
      for (int j = 0; j < 4; ++j)
        rv[j] = *(const f32x4*)(Vsrc + (size_t)(4 * kq + j) * DH + d0);
      #pragma unroll
      for (int j2 = 0; j2 < 4; ++j2) {
        const int dd = d0 + j2;
        uint2 w = make_uint2(pk2(rv[0][j2], rv[1][j2]), pk2(rv[2][j2], rv[3][j2]));
        *(uint2*)(Vdst + ((dd * 128 + 8 * kq) ^ ((dd & 7) << 4))) = w;
      }
    }
  }
}

// ---------------- pass 2: flash attention, T15 2-deep pipeline ----------------
__global__ __launch_bounds__(256, 2)
void attn_fwd(const float* __restrict__ Qg, const char* __restrict__ wsK,
              const char* __restrict__ wsV, float* __restrict__ Og) {
  // K dbuf: 2 x 16KB @0 (staged 2-ahead); Vt dbuf: 2 x 16KB @32768 (staged 1-ahead).
  __shared__ __align__(16) char smem[65536];

  const int tid  = threadIdx.x;
  const int wid  = tid >> 6;
  const int lane = tid & 63;
  const int hi   = lane >> 5;
  const int c    = lane & 31;

  // complementary-pair decode (R6/R11-verified)
  const int i   = blockIdx.x;
  const int p   = i & 1;
  const int q3  = (i >> 1) & 7;
  const int b   = (i >> 4) & 31;
  const int qtb = (b & 16) ? (15 - q3) : q3;
  const int qt  = p ? qtb : (15 - qtb);
  const int qb  = qt * QBLK;
  const int nt  = 2 * qt + 2;          // always even

  const float* Qb = Qg + (size_t)b * SQL * DH;
  float* Ob = Og + (size_t)b * SQL * DH;
  const char* Ktiles = wsK + (size_t)b * NKT * TILEB;
  const char* Vtiles = wsV + (size_t)b * NKT * TILEB;

  const float qscale = 0.08838834764831845f * 1.4426950408889634f;

  // ---- Q fragments (B-operand of swapped QK^T, 32x32x16)
  s16x8 qf[8];
  {
    const float* qr = Qb + (size_t)(qb + 32*wid + c) * DH + 8*hi;
    #pragma unroll
    for (int ds = 0; ds < 8; ++ds) {
      f32x4 a = *(const f32x4*)(qr + 16*ds);
      f32x4 d = *(const f32x4*)(qr + 16*ds + 4);
      u32x4 w;
      w[0] = pk2(a[0]*qscale, a[1]*qscale);
      w[1] = pk2(a[2]*qscale, a[3]*qscale);
      w[2] = pk2(d[0]*qscale, d[1]*qscale);
      w[3] = pk2(d[2]*qscale, d[3]*qscale);
      qf[ds] = __builtin_bit_cast(s16x8, w);
    }
  }

  f32x16 oacc[4];
  #pragma unroll
  for (int nb = 0; nb < 4; ++nb) oacc[nb] = (f32x16){0.f};
  float m_run = -1e30f, l_run = 0.f;   // l_run: per-half partial (epilogue combines)

  const int qglob = qb + 32*wid + c;
  const int qhiw  = qb + 32*wid + 31;
  const int qlow  = qb + 32*wid;

  auto STAGE_K = [&](int t) {          // Kbuf[t&1], 4 x global_load_lds
    const char* ks = Ktiles + (size_t)t * TILEB + tid * 16;
    char* kl = smem + (t & 1) * 16384 + wid * 1024;
    #pragma unroll
    for (int jj = 0; jj < 4; ++jj)
      __builtin_amdgcn_global_load_lds(AS1(ks + jj*4096), AS3(kl + jj*4096), 16, 0, 0);
  };
  auto STAGE_V = [&](int t) {          // Vbuf[t&1], 4 x global_load_lds
    const char* vs = Vtiles + (size_t)t * TILEB + tid * 16;
    char* vl = smem + 32768 + (t & 1) * 16384 + wid * 1024;
    #pragma unroll
    for (int jj = 0; jj < 4; ++jj)
      __builtin_amdgcn_global_load_lds(AS1(vs + jj*4096), AS3(vl + jj*4096), 16, 0, 0);
  };

  // QK^T of tile t -> sacc (incl. causal mask). Reads Kbuf[t&1].
  auto QKT = [&](int t, f32x16* sacc) {
    const char* Kl = smem + (t & 1) * 16384;
    sacc[0] = (f32x16){0.f};
    sacc[1] = (f32x16){0.f};
    __builtin_amdgcn_s_setprio(1);
    #pragma unroll
    for (int ds = 0; ds < 8; ++ds) {
      #pragma unroll
      for (int mb = 0; mb < 2; ++mb) {
        const int row = 32*mb + c;
        s16x8 kf = *(const s16x8*)(Kl + ((row*256 + 32*ds + 16*hi) ^ ((c & 7) << 4)));
        sacc[mb] = __builtin_amdgcn_mfma_f32_32x32x16_bf16(kf, qf[ds], sacc[mb], 0, 0, 0);
      }
    }
    __builtin_amdgcn_s_setprio(0);
    const int kb = t * KBLK;
    if (kb + KBLK - 1 > qlow) {
      #pragma unroll
      for (int mb = 0; mb < 2; ++mb)
        #pragma unroll
        for (int r = 0; r < 16; ++r) {
          const int kk = kb + 32*mb + (r & 3) + 8*(r >> 2) + 4*hi;
          if (kk > qglob) sacc[mb][r] = -1e30f;
        }
    }
  };

  // softmax + PV of tile t (sacc already masked). Reads Vbuf[t&1].
  auto SMPV = [&](int t, f32x16* sacc) {
    const char* Vl = smem + 32768 + (t & 1) * 16384;

    float mx[8];
    #pragma unroll
    for (int e = 0; e < 8; ++e)
      mx[e] = fmaxf(fmaxf(sacc[0][e], sacc[0][e+8]), fmaxf(sacc[1][e], sacc[1][e+8]));
    mx[0] = fmaxf(mx[0], mx[4]); mx[1] = fmaxf(mx[1], mx[5]);
    mx[2] = fmaxf(mx[2], mx[6]); mx[3] = fmaxf(mx[3], mx[7]);
    const float tmax = fmaxf(fmaxf(mx[0], mx[1]), fmaxf(mx[2], mx[3]));

    if (!__all(tmax <= m_run + 8.0f)) {            // defer-max (T13)
      float tfull = fmaxf(tmax, __shfl_xor(tmax, 32));
      const float mnew  = fmaxf(m_run, tfull);
      const float alpha = exp2f(m_run - mnew);
      #pragma unroll
      for (int r = 0; r < 16; ++r) {
        float av = __shfl(alpha, (r & 3) + 8*(r >> 2) + 4*hi);
        #pragma unroll
        for (int nb = 0; nb < 4; ++nb) oacc[nb][r] *= av;
      }
      l_run *= alpha;
      m_run = mnew;
    }

    float lsa = 0.f, lsb = 0.f;
    unsigned int u0[8], u1[8];
    #pragma unroll
    for (int w = 0; w < 8; ++w) {
      float p0 = exp2f(sacc[0][2*w]     - m_run);
      float p1 = exp2f(sacc[0][2*w + 1] - m_run);
      lsa += p0 + p1;
      u0[w] = cvtpk_bf16(p0, p1);
    }
    #pragma unroll
    for (int w = 0; w < 8; ++w) {
      float p0 = exp2f(sacc[1][2*w]     - m_run);
      float p1 = exp2f(sacc[1][2*w + 1] - m_run);
      lsb += p0 + p1;
      u1[w] = cvtpk_bf16(p0, p1);
    }
    l_run += lsa + lsb;                            // per-half partial

    PLSWAP(u0[0], u0[2]); PLSWAP(u0[1], u0[3]);
    PLSWAP(u0[4], u0[6]); PLSWAP(u0[5], u0[7]);
    PLSWAP(u1[0], u1[2]); PLSWAP(u1[1], u1[3]);
    PLSWAP(u1[4], u1[6]); PLSWAP(u1[5], u1[7]);
    s16x8 pa[4];
    { u32x4 w = {u0[0], u0[1], u0[2], u0[3]}; pa[0] = __builtin_bit_cast(s16x8, w); }
    { u32x4 w = {u0[4], u0[5], u0[6], u0[7]}; pa[1] = __builtin_bit_cast(s16x8, w); }
    { u32x4 w = {u1[0], u1[1], u1[2], u1[3]}; pa[2] = __builtin_bit_cast(s16x8, w); }
    { u32x4 w = {u1[4], u1[5], u1[6], u1[7]}; pa[3] = __builtin_bit_cast(s16x8, w); }

    __builtin_amdgcn_s_setprio(1);
    #pragma unroll
    for (int nb = 0; nb < 4; ++nb) {
      #pragma unroll
      for (int ks = 0; ks < 4; ++ks) {
        const int row = 32*nb + c;
        s16x8 vf = *(const s16x8*)(Vl + ((row*128 + 32*ks + 16*hi) ^ ((c & 7) << 4)));
        oacc[nb] = __builtin_amdgcn_mfma_f32_32x32x16_bf16(pa[ks], vf, oacc[nb], 0, 0, 0);
      }
    }
    __builtin_amdgcn_s_setprio(0);
  };

  // prologue: K 2-ahead, V 1-ahead. Issue order K0,K1,V0 makes vmcnt suffixes exact.
  STAGE_K(0);
  STAGE_K(1);
  STAGE_V(0);

  f32x16 sA[2], sB[2];

  for (int u = 0; u < nt; u += 2) {
    // ---- phase A (t = u): QK^T(u) || SMPV(u-1)
    // top wait: K(u) [and V(u-1)] done; in flight: K(u+1), V(u) = 8.
    asm volatile("s_waitcnt vmcnt(8)" ::: "memory");
    __builtin_amdgcn_s_barrier();
    __builtin_amdgcn_sched_barrier(0);

    QKT(u, sA);                              // u <= nt-2 -> always active
    if (u > 0) SMPV(u - 1, sB);              // (u-1)*64 < qb <= qhiw: always active

    __builtin_amdgcn_s_barrier();
    if (u + 2 < nt) STAGE_K(u + 2);          // rewrites Kbuf[u&1] (just read)
    STAGE_V(u + 1);                          // rewrites Vbuf[(u+1)&1] (= (u-1)&1, just read)

    // ---- phase B (t = u+1): QK^T(u+1) || SMPV(u)
    // top wait: V(u) [and K(u+1)] done; in flight: K(u+2)?, V(u+1).
    if (u + 2 < nt) asm volatile("s_waitcnt vmcnt(8)" ::: "memory");
    else            asm volatile("s_waitcnt vmcnt(4)" ::: "memory");
    __builtin_amdgcn_s_barrier();
    __builtin_amdgcn_sched_barrier(0);

    if ((u + 1) * KBLK <= qhiw) QKT(u + 1, sB);   // last tile: only upper waves
    SMPV(u, sA);                                  // u*64 <= qb <= qhiw: always active

    __builtin_amdgcn_s_barrier();
    if (u + 3 < nt) STAGE_K(u + 3);
    if (u + 2 < nt) STAGE_V(u + 2);
  }

  // ---- tail: SMPV of the last tile (waves whose rows reach it)
  asm volatile("s_waitcnt vmcnt(0)" ::: "memory");
  __builtin_amdgcn_s_barrier();
  if ((nt - 1) * KBLK <= qhiw) SMPV(nt - 1, sB);

  // ---- epilogue: combine l halves once, store O
  const float l_tot = l_run + __shfl_xor(l_run, 32);
  const float linv  = 1.0f / l_tot;
  float* Orow = Ob + (size_t)(qb + 32*wid) * DH;
  #pragma unroll
  for (int r = 0; r < 16; ++r) {
    const int q = (r & 3) + 8*(r >> 2) + 4*hi;
    float lv = __shfl(linv, q);
    #pragma unroll
    for (int nb = 0; nb < 4; ++nb)
      Orow[(size_t)q * DH + 32*nb + c] = oacc[nb][r] * lv;
  }
}

extern "C" void kernel_launch(void* const* d_in, const int* in_sizes, int n_in,
                              void* d_out, int out_size, void* d_ws, size_t ws_size,
                              hipStream_t stream) {
  const float* Q = (const float*)d_in[0];
  const float* K = (const float*)d_in[1];
  const float* V = (const float*)d_in[2];
  // d_in[3]: causal mask, deterministic (triu k=1) -> synthesized in-kernel
  float* O = (float*)d_out;
  char* wsK = (char*)d_ws;                                   // 16 MB
  char* wsV = (char*)d_ws + (size_t)NB * NKT * TILEB;        // 16 MB

  prep_kv<<<dim3(NB * NKT), dim3(256), 0, stream>>>(K, V, wsK, wsV);
  attn_fwd<<<dim3(NB * (SQL / QBLK)), dim3(256), 0, stream>>>(Q, wsK, wsV, O);
}

// Round 13
// 86.720 us; speedup vs baseline: 2.2266x; 1.0070x over previous
//
#include <hip/hip_runtime.h>
#include <hip/hip_bf16.h>

#define NB   32
#define SQL  2048
#define DH   128
#define QBLK 128
#define KBLK 64
#define NKT  (SQL / KBLK)      // 32 k-tiles per batch
#define TILEB 16384            // bytes per (64x128 bf16) tile image

typedef __attribute__((ext_vector_type(4)))  float f32x4;
typedef __attribute__((ext_vector_type(16))) float f32x16;
typedef __attribute__((ext_vector_type(8)))  short s16x8;
typedef __attribute__((ext_vector_type(4)))  unsigned int u32x4;

__device__ __forceinline__ unsigned int cvtpk_bf16(float lo, float hi) {
  unsigned int r;
  asm("v_cvt_pk_bf16_f32 %0, %1, %2" : "=v"(r) : "v"(lo), "v"(hi));
  return r;
}
// x.hi32lanes = y.lo32lanes ; y.lo32lanes = x.hi32lanes_old
#define PLSWAP(x, y) asm volatile("v_permlane32_swap_b32 %0, %1" : "+v"(x), "+v"(y))

__device__ __forceinline__ unsigned int pk2(float lo, float hi) {
  unsigned short a = __builtin_bit_cast(unsigned short, __float2bfloat16(lo));
  unsigned short b = __builtin_bit_cast(unsigned short, __float2bfloat16(hi));
  return (unsigned int)a | ((unsigned int)b << 16);
}

#define AS1(p) ((const __attribute__((address_space(1))) void*)(p))
#define AS3(p) ((__attribute__((address_space(3))) void*)(p))

// ---------------- pass 1: K/V -> bf16 tiles in pre-swizzled LDS-image layout ----
// K image:  img[(r*256 + 2*d) ^ ((r&7)<<4)]  = bf16(K[r][d])   (r = k-row 0..63)
// Vt image: img[(d*128 + 2*k) ^ ((d&7)<<4)]  = bf16(V[k][d])   (d = 0..127, k = 0..63)
__global__ __launch_bounds__(256)
void prep_kv(const float* __restrict__ Kg, const float* __restrict__ Vg,
             char* __restrict__ wsK, char* __restrict__ wsV) {
  const int blk = blockIdx.x;          // b*32 + kt
  const int b   = blk >> 5;
  const int kt  = blk & 31;
  const int tid = threadIdx.x;
  const float* Ksrc = Kg + ((size_t)b * SQL + (size_t)kt * KBLK) * DH;
  const float* Vsrc = Vg + ((size_t)b * SQL + (size_t)kt * KBLK) * DH;
  char* Kdst = wsK + (size_t)blk * TILEB;
  char* Vdst = wsV + (size_t)blk * TILEB;

  {  // K: row-major bf16, swizzled
    const int q16 = tid & 15;
    const int r0  = tid >> 4;
    #pragma unroll
    for (int it = 0; it < 4; ++it) {
      const int r = r0 + 16 * it;
      const float* src = Ksrc + (size_t)r * DH + 8 * q16;
      f32x4 a = *(const f32x4*)(src);
      f32x4 d = *(const f32x4*)(src + 4);
      u32x4 w;
      w[0] = pk2(a[0], a[1]); w[1] = pk2(a[2], a[3]);
      w[2] = pk2(d[0], d[1]); w[3] = pk2(d[2], d[3]);
      *(u32x4*)(Kdst + ((r * 256 + 16 * q16) ^ ((r & 7) << 4))) = w;
    }
  }
  {  // V: transposed Vt[d][k], swizzled (4x4 register transpose)
    const int kq = tid & 15;
    const int dq = tid >> 4;
    #pragma unroll
    for (int it = 0; it < 2; ++it) {
      const int d0 = 4 * dq + 64 * it;
      f32x4 rv[4];
      #pragma unroll
      for (int j = 0; j < 4; ++j)
        rv[j] = *(const f32x4*)(Vsrc + (size_t)(4 * kq + j) * DH + d0);
      #pragma unroll
      for (int j2 = 0; j2 < 4; ++j2) {
        const int dd = d0 + j2;
        uint2 w = make_uint2(pk2(rv[0][j2], rv[1][j2]), pk2(rv[2][j2], rv[3][j2]));
        *(uint2*)(Vdst + ((dd * 128 + 8 * kq) ^ ((dd & 7) << 4))) = w;
      }
    }
  }
}

// ---------------- pass 2: flash attention, 32 q-rows/wave, global_load_lds ------
__global__ __launch_bounds__(256, 2)
void attn_fwd(const float* __restrict__ Qg, const char* __restrict__ wsK,
              const char* __restrict__ wsV, float* __restrict__ Og) {
  // K dbuf: 2 x 16KB @0; Vt dbuf: 2 x 16KB @32768. No P buffer (in-register).
  __shared__ __align__(16) char smem[65536];

  const int tid  = threadIdx.x;
  const int wid  = tid >> 6;
  const int lane = tid & 63;
  const int hi   = lane >> 5;
  const int c    = lane & 31;

  // SAME-BATCH complementary CU-pairing: under round-robin dispatch, blocks
  // i and i+256 land on the same CU. Decode gives them the SAME batch b and
  // complementary q-tiles (qt, 15-qt): nt sums to 34 (static balance) AND the
  // two co-resident blocks read the same k-tile stream -> second reader hits
  // the XCD L2 (halves L3 demand + latency).
  const int i    = blockIdx.x;
  const int half = i >> 8;
  const int j    = i & 255;
  const int b    = j & 31;
  const int q3   = j >> 5;             // 0..7
  const int qt   = half ? (15 - q3) : q3;
  const int qb   = qt * QBLK;
  const int nt   = 2 * qt + 2;

  const float* Qb = Qg + (size_t)b * SQL * DH;
  float* Ob = Og + (size_t)b * SQL * DH;
  const char* Ktiles = wsK + (size_t)b * NKT * TILEB;
  const char* Vtiles = wsV + (size_t)b * NKT * TILEB;

  const float qscale = 0.08838834764831845f * 1.4426950408889634f;  // 1/sqrt(128)*log2e

  // ---- Q fragments (B-operand of swapped QK^T, 32x32x16):
  // lane (hi,c) holds Q[q = qb+32*wid+c][d = 16*ds + 8*hi + j], j=0..7
  s16x8 qf[8];
  {
    const float* qr = Qb + (size_t)(qb + 32*wid + c) * DH + 8*hi;
    #pragma unroll
    for (int ds = 0; ds < 8; ++ds) {
      f32x4 a = *(const f32x4*)(qr + 16*ds);
      f32x4 d = *(const f32x4*)(qr + 16*ds + 4);
      u32x4 w;
      w[0] = pk2(a[0]*qscale, a[1]*qscale);
      w[1] = pk2(a[2]*qscale, a[3]*qscale);
      w[2] = pk2(d[0]*qscale, d[1]*qscale);
      w[3] = pk2(d[2]*qscale, d[3]*qscale);
      qf[ds] = __builtin_bit_cast(s16x8, w);
    }
  }

  f32x16 oacc[4];
  #pragma unroll
  for (int nb = 0; nb < 4; ++nb) oacc[nb] = (f32x16){0.f};
  // l_run: per-half partial (epilogue combines); alpha row-uniform so exact.
  float m_run = -1e30f, l_run = 0.f;

  const int qglob = qb + 32*wid + c;
  const int qhiw  = qb + 32*wid + 31;
  const int qlow  = qb + 32*wid;

  // stage tile t into LDS buf (t&1): 8 x global_load_lds (4 K + 4 Vt), 16B/lane
  auto STAGE = [&](int t) {
    const char* ks = Ktiles + (size_t)t * TILEB + tid * 16;
    const char* vs = Vtiles + (size_t)t * TILEB + tid * 16;
    char* kl = smem + (t & 1) * 16384 + wid * 1024;
    char* vl = smem + 32768 + (t & 1) * 16384 + wid * 1024;
    #pragma unroll
    for (int jj = 0; jj < 4; ++jj) {
      __builtin_amdgcn_global_load_lds(AS1(ks + jj * 4096), AS3(kl + jj * 4096), 16, 0, 0);
      __builtin_amdgcn_global_load_lds(AS1(vs + jj * 4096), AS3(vl + jj * 4096), 16, 0, 0);
    }
  };

  STAGE(0);
  STAGE(1);   // nt >= 2 always

  for (int t = 0; t < nt; ++t) {
    // counted vmcnt: tile t's 8 loads are oldest; tile t+1's 8 stay in flight
    if (t == nt - 1) asm volatile("s_waitcnt vmcnt(0)" ::: "memory");
    else             asm volatile("s_waitcnt vmcnt(8)" ::: "memory");
    __builtin_amdgcn_s_barrier();
    __builtin_amdgcn_sched_barrier(0);

    const int kb = t * KBLK;
    const char* Kl = smem + (t & 1) * 16384;
    const char* Vl = smem + 32768 + (t & 1) * 16384;

    if (kb <= qhiw) {
      // ---- QK^T swapped: S^T[k][q], A = K from LDS, B = Q regs
      f32x16 sacc[2];
      sacc[0] = (f32x16){0.f};
      sacc[1] = (f32x16){0.f};
      __builtin_amdgcn_s_setprio(1);
      #pragma unroll
      for (int ds = 0; ds < 8; ++ds) {
        #pragma unroll
        for (int mb = 0; mb < 2; ++mb) {
          const int row = 32*mb + c;
          s16x8 kf = *(const s16x8*)(Kl + ((row*256 + 32*ds + 16*hi) ^ ((c & 7) << 4)));
          sacc[mb] = __builtin_amdgcn_mfma_f32_32x32x16_bf16(kf, qf[ds], sacc[mb], 0, 0, 0);
        }
      }
      __builtin_amdgcn_s_setprio(0);

      // ---- causal mask (diag-crossing tiles): lane holds S^T[k=kb+32mb+crow(r,hi)][q=c]
      if (kb + KBLK - 1 > qlow) {
        #pragma unroll
        for (int mb = 0; mb < 2; ++mb)
          #pragma unroll
          for (int r = 0; r < 16; ++r) {
            const int kk = kb + 32*mb + (r & 3) + 8*(r >> 2) + 4*hi;
            if (kk > qglob) sacc[mb][r] = -1e30f;
          }
      }

      // ---- per-half row max (tree); no cross-half shuffle on the fast path
      float mx[8];
      #pragma unroll
      for (int e = 0; e < 8; ++e)
        mx[e] = fmaxf(fmaxf(sacc[0][e], sacc[0][e+8]), fmaxf(sacc[1][e], sacc[1][e+8]));
      mx[0] = fmaxf(mx[0], mx[4]); mx[1] = fmaxf(mx[1], mx[5]);
      mx[2] = fmaxf(mx[2], mx[6]); mx[3] = fmaxf(mx[3], mx[7]);
      const float tmax = fmaxf(fmaxf(mx[0], mx[1]), fmaxf(mx[2], mx[3]));

      // ---- defer-max (T13): rescale only when some row's max grew by > 8
      if (!__all(tmax <= m_run + 8.0f)) {
        float tfull = fmaxf(tmax, __shfl_xor(tmax, 32));   // shuffle only on rare path
        const float mnew  = fmaxf(m_run, tfull);
        const float alpha = exp2f(m_run - mnew);
        #pragma unroll
        for (int r = 0; r < 16; ++r) {
          float av = __shfl(alpha, (r & 3) + 8*(r >> 2) + 4*hi);
          #pragma unroll
          for (int nb = 0; nb < 4; ++nb) oacc[nb][r] *= av;
        }
        l_run *= alpha;
        m_run = mnew;
      }

      // ---- p = exp2(s - m) interleaved with pack; l accumulated per-half only
      float lsa = 0.f, lsb = 0.f;
      unsigned int u0[8], u1[8];
      #pragma unroll
      for (int w = 0; w < 8; ++w) {
        float p0 = exp2f(sacc[0][2*w]     - m_run);
        float p1 = exp2f(sacc[0][2*w + 1] - m_run);
        lsa += p0 + p1;
        u0[w] = cvtpk_bf16(p0, p1);
      }
      #pragma unroll
      for (int w = 0; w < 8; ++w) {
        float p0 = exp2f(sacc[1][2*w]     - m_run);
        float p1 = exp2f(sacc[1][2*w + 1] - m_run);
        lsb += p0 + p1;
        u1[w] = cvtpk_bf16(p0, p1);
      }
      l_run += lsa + lsb;      // no per-tile cross-half shuffle (epilogue combines)

      // ---- in-register P -> PV A-frags via permlane32_swap (T12, HW-verified)
      PLSWAP(u0[0], u0[2]); PLSWAP(u0[1], u0[3]);
      PLSWAP(u0[4], u0[6]); PLSWAP(u0[5], u0[7]);
      PLSWAP(u1[0], u1[2]); PLSWAP(u1[1], u1[3]);
      PLSWAP(u1[4], u1[6]); PLSWAP(u1[5], u1[7]);
      s16x8 pa[4];
      { u32x4 w = {u0[0], u0[1], u0[2], u0[3]}; pa[0] = __builtin_bit_cast(s16x8, w); }
      { u32x4 w = {u0[4], u0[5], u0[6], u0[7]}; pa[1] = __builtin_bit_cast(s16x8, w); }
      { u32x4 w = {u1[0], u1[1], u1[2], u1[3]}; pa[2] = __builtin_bit_cast(s16x8, w); }
      { u32x4 w = {u1[4], u1[5], u1[6], u1[7]}; pa[3] = __builtin_bit_cast(s16x8, w); }

      // ---- PV: O[q][d] += P[q][k] Vt[d][k]^T  (A = P regs, B = V from LDS)
      __builtin_amdgcn_s_setprio(1);
      #pragma unroll
      for (int nb = 0; nb < 4; ++nb) {
        #pragma unroll
        for (int ks = 0; ks < 4; ++ks) {
          const int row = 32*nb + c;
          s16x8 vf = *(const s16x8*)(Vl + ((row*128 + 32*ks + 16*hi) ^ ((c & 7) << 4)));
          oacc[nb] = __builtin_amdgcn_mfma_f32_32x32x16_bf16(pa[ks], vf, oacc[nb], 0, 0, 0);
        }
      }
      __builtin_amdgcn_s_setprio(0);
    }

    __builtin_amdgcn_s_barrier();     // all waves done reading buf (t&1)
    if (t + 2 < nt) STAGE(t + 2);     // refill it for tile t+2
  }

  // ---- epilogue: combine l halves once, store O
  const float l_tot = l_run + __shfl_xor(l_run, 32);
  const float linv  = 1.0f / l_tot;
  float* Orow = Ob + (size_t)(qb + 32*wid) * DH;
  #pragma unroll
  for (int r = 0; r < 16; ++r) {
    const int q = (r & 3) + 8*(r >> 2) + 4*hi;
    float lv = __shfl(linv, q);
    #pragma unroll
    for (int nb = 0; nb < 4; ++nb)
      Orow[(size_t)q * DH + 32*nb + c] = oacc[nb][r] * lv;
  }
}

extern "C" void kernel_launch(void* const* d_in, const int* in_sizes, int n_in,
                              void* d_out, int out_size, void* d_ws, size_t ws_size,
                              hipStream_t stream) {
  const float* Q = (const float*)d_in[0];
  const float* K = (const float*)d_in[1];
  const float* V = (const float*)d_in[2];
  // d_in[3]: causal mask, deterministic (triu k=1) -> synthesized in-kernel
  float* O = (float*)d_out;
  char* wsK = (char*)d_ws;                                   // 16 MB
  char* wsV = (char*)d_ws + (size_t)NB * NKT * TILEB;        // 16 MB

  prep_kv<<<dim3(NB * NKT), dim3(256), 0, stream>>>(K, V, wsK, wsV);
  attn_fwd<<<dim3(NB * (SQL / QBLK)), dim3(256), 0, stream>>>(Q, wsK, wsV, O);
}